// Round 7
// baseline (544.100 us; speedup 1.0000x reference)
//
#include <hip/hip_runtime.h>
#include <hip/hip_bf16.h>
#include <cstdint>
#include <math.h>

#define NDIM 1024
#define BDIM 32
#define DDIM 64
#define NEDGE 5
#define NROWS (BDIM * NDIM)

struct Keys { uint32_t a[NEDGE]; uint32_t b[NEDGE]; };

// Single-instruction rotate (v_alignbit_b32 via fshl).
#if __has_builtin(__builtin_rotateleft32)
#define ROTL32(x, r) __builtin_rotateleft32((x), (r))
#else
#define ROTL32(x, r) (((x) << (r)) | ((x) >> (32 - (r))))
#endif

// JAX Threefry-2x32, 20 rounds. Matches jax/_src/prng.py exactly.
#define TF_R(r) do { x0 += x1; x1 = ROTL32(x1, r); x1 ^= x0; } while (0)
__host__ __device__ inline void tf2x32(uint32_t k0, uint32_t k1,
                                       uint32_t x0, uint32_t x1,
                                       uint32_t& o0, uint32_t& o1) {
  const uint32_t ks2 = k0 ^ k1 ^ 0x1BD11BDAu;
  x0 += k0; x1 += k1;
  TF_R(13); TF_R(15); TF_R(26); TF_R(6);
  x0 += k1; x1 += ks2 + 1u;
  TF_R(17); TF_R(29); TF_R(16); TF_R(24);
  x0 += ks2; x1 += k0 + 2u;
  TF_R(13); TF_R(15); TF_R(26); TF_R(6);
  x0 += k0; x1 += k1 + 3u;
  TF_R(17); TF_R(29); TF_R(16); TF_R(24);
  x0 += k1; x1 += ks2 + 4u;
  TF_R(13); TF_R(15); TF_R(26); TF_R(6);
  x0 += ks2; x1 += k0 + 5u;
  o0 = x0; o1 = x1;
}

// Partitionable threefry bits for linear position p: o0^o1 of tf(key; 0, p).
__device__ __forceinline__ uint32_t tf_bits(uint32_t k0, uint32_t k1, uint32_t p) {
  uint32_t o0, o1;
  tf2x32(k0, k1, 0u, p, o0, o1);
  return o0 ^ o1;
}

// bits -> uniform(1e-10,1) -> gumbel, replicating JAX's exact f32 op sequence
// (separate mul/add rounding — no FMA contraction), double-precision logs.
__device__ __forceinline__ float gumbel_bits(uint32_t bits) {
  float f = __uint_as_float((bits >> 9) | 0x3F800000u) - 1.0f;
  float u = fmaxf(1e-10f, __fadd_rn(__fmul_rn(f, 1.0f - 1e-10f), 1e-10f));
  float t = -(float)log((double)u);
  return -(float)log((double)t);
}

__global__ void k_init(int* __restrict__ ctr) {
  if (threadIdx.x == 0) *ctr = 0;
}

// Phase A: logits[b][n] = W2 . tanh(W1^T [curr_b; nodes_bn] + b1) + b2
__global__ __launch_bounds__(256) void k_logits(
    const float* __restrict__ nodes, const int* __restrict__ nn,
    const float* __restrict__ W1, const float* __restrict__ b1,
    const float* __restrict__ W2, const float* __restrict__ b2,
    float* __restrict__ logits) {
  const int lane = threadIdx.x & 63;
  const int gw = (blockIdx.x * 256 + threadIdx.x) >> 6;   // wave id = (b,n)
  const int b = gw >> 10, n = gw & (NDIM - 1);
  const int cn = nn[b];
  const float a = nodes[((size_t)b * NDIM + cn) * DDIM + lane];  // curr
  const float x = nodes[((size_t)b * NDIM + n) * DDIM + lane];
  float acc = b1[lane];
#pragma unroll 8
  for (int k = 0; k < 64; ++k)
    acc = fmaf(__shfl(a, k), W1[k * DDIM + lane], acc);
#pragma unroll 8
  for (int k = 0; k < 64; ++k)
    acc = fmaf(__shfl(x, k), W1[(64 + k) * DDIM + lane], acc);
  float p = tanhf(acc) * W2[lane];
  for (int off = 32; off; off >>= 1) p += __shfl_down(p, off);
  if (lane == 0) logits[b * NDIM + n] = p + b2[0];
}

// Fused phase: PERSISTENT waves + atomic row queue. Each wave repeatedly
// claims one (b,r) row, hash-argmaxes it, and streams adj/weights rows.
// Online scheduling kills the static-map straggler tail (r4/r6: Occ 33%).
__global__ __launch_bounds__(256) void k_main(
    const float* __restrict__ adj_in, const float* __restrict__ w_in,
    const float* __restrict__ logits, const int* __restrict__ nn_arr,
    float* __restrict__ adj_out, float* __restrict__ w_out,
    int* __restrict__ ctr, Keys keys) {
  const int lane = threadIdx.x & 63;

  for (;;) {
    int gw0 = 0;
    if (lane == 0) gw0 = atomicAdd(ctr, 1);
    const int gw = __shfl(gw0, 0);
    if (gw >= NROWS) return;

    const int b = gw >> 10;
    const int r = gw & (NDIM - 1);
    const int nn = nn_arr[b];
    const size_t row = (size_t)gw << 10;

    int bc[NEDGE];
#pragma unroll
    for (int e = 0; e < NEDGE; ++e) bc[e] = NDIM;   // sentinel: no hit

    if (r <= nn) {   // wave-uniform branch
      int bv[NEDGE], bcl[NEDGE];
#pragma unroll
      for (int e = 0; e < NEDGE; ++e) { bv[e] = -1; bcl[e] = NDIM; }
      bool wnz = false;
      for (int c = lane; c <= nn; c += 64) {
        float w = w_in[row + c];
        if (r == nn && c < nn) w = logits[(b << 10) + c];
        wnz |= (w != 0.f);
        const uint32_t p = (uint32_t)row + (uint32_t)c;
#pragma unroll
        for (int e = 0; e < NEDGE; ++e) {
          // gumbel monotone in bits>>9; per-lane c ascending -> strict '>'
          // keeps smallest c per lane automatically.
          const int v = (int)(tf_bits(keys.a[e], keys.b[e], p) >> 9);
          if (v > bv[e]) { bv[e] = v; bcl[e] = c; }
        }
      }
      if (__ballot(wnz)) {
        // float fallback: only rows with nonzero weights (patched logit row)
        uint32_t fk[NEDGE]; int fc[NEDGE];
#pragma unroll
        for (int e = 0; e < NEDGE; ++e) { fk[e] = 0u; fc[e] = NDIM; }
        for (int c = lane; c <= nn; c += 64) {
          float w = w_in[row + c];
          if (r == nn && c < nn) w = logits[(b << 10) + c];
          const uint32_t p = (uint32_t)row + (uint32_t)c;
#pragma unroll
          for (int e = 0; e < NEDGE; ++e) {
            const float pert = w + gumbel_bits(tf_bits(keys.a[e], keys.b[e], p));
            const uint32_t fu = __float_as_uint(pert);
            const uint32_t key = (fu & 0x80000000u) ? ~fu : (fu | 0x80000000u);
            if (key > fk[e]) { fk[e] = key; fc[e] = c; }
          }
        }
#pragma unroll
        for (int e = 0; e < NEDGE; ++e) {
          uint32_t k = fk[e]; int c = fc[e];
          for (int off = 32; off; off >>= 1) {
            const uint32_t ko = __shfl_xor(k, off);
            const int co = __shfl_xor(c, off);
            if (ko > k || (ko == k && co < c)) { k = ko; c = co; }
          }
          bc[e] = c;   // butterfly: all lanes hold the result
        }
      } else {
#pragma unroll
        for (int e = 0; e < NEDGE; ++e) {
          int v = bv[e]; int c = bcl[e];
          for (int off = 32; off; off >>= 1) {
            const int vo = __shfl_xor(v, off);
            const int co = __shfl_xor(c, off);
            if (vo > v || (vo == v && co < c)) { v = vo; c = co; }
          }
          bc[e] = c;
        }
      }
    }

    // Streaming epilogue: 4 float4 per lane per row, lane-coalesced.
    const float4* a4 = (const float4*)(adj_in + row);
    const float4* w4 = (const float4*)(w_in + row);
    float4* ao4 = (float4*)(adj_out + row);
    float4* wo4 = (float4*)(w_out + row);
    const bool patch = (r == nn);
#pragma unroll
    for (int k = 0; k < 4; ++k) {
      const int idx = (k << 6) | lane;
      float4 v = a4[idx];
      float4 wv = w4[idx];
      float* vf = (float*)&v;
      float* wf = (float*)&wv;
      const int c0 = idx << 2;
#pragma unroll
      for (int jx = 0; jx < 4; ++jx) {
        const int c = c0 + jx;
        float f = vf[jx];
        if (c == bc[0] || c == bc[1] || c == bc[2] || c == bc[3] || c == bc[4])
          f = 1.0f;
        if (c == r) f = 0.0f;
        vf[jx] = f;
        if (patch && c < nn) wf[jx] = logits[(b << 10) + c];
      }
      ao4[idx] = v;
      wo4[idx] = wv;
    }
  }
}

extern "C" void kernel_launch(void* const* d_in, const int* in_sizes, int n_in,
                              void* d_out, int out_size, void* d_ws, size_t ws_size,
                              hipStream_t stream) {
  (void)in_sizes; (void)n_in; (void)out_size; (void)ws_size;
  const float* nodes = (const float*)d_in[0];
  const float* adj   = (const float*)d_in[1];
  const float* wts   = (const float*)d_in[2];
  const int*   nn    = (const int*)d_in[3];
  const float* W1    = (const float*)d_in[5];
  const float* b1    = (const float*)d_in[6];
  const float* W2    = (const float*)d_in[7];
  const float* b2    = (const float*)d_in[8];

  float* adj_out = (float*)d_out;
  float* w_out   = adj_out + (size_t)BDIM * NDIM * NDIM;
  float* logits  = (float*)d_ws;                            // 128 KB
  int*   ctr     = (int*)((char*)d_ws + (size_t)NROWS * 4); // queue counter

  // folded keys: k_i = threefry2x32(key=(0,42), data=(0,i))  [jax.random.fold_in]
  Keys keys;
  for (int i = 0; i < NEDGE; ++i) {
    uint32_t o0, o1;
    tf2x32(0u, 42u, 0u, (uint32_t)i, o0, o1);
    keys.a[i] = o0; keys.b[i] = o1;
  }

  k_init  <<<dim3(1), 64, 0, stream>>>(ctr);
  k_logits<<<dim3(BDIM * NDIM / 4), 256, 0, stream>>>(nodes, nn, W1, b1, W2, b2, logits);
  k_main  <<<dim3(2048), 256, 0, stream>>>(adj, wts, logits, nn, adj_out, w_out, ctr, keys);
}

// Round 8
// 292.342 us; speedup vs baseline: 1.8612x; 1.8612x over previous
//
#include <hip/hip_runtime.h>
#include <hip/hip_bf16.h>
#include <cstdint>
#include <math.h>

#define NDIM 1024
#define BDIM 32
#define DDIM 64
#define NEDGE 5

struct Keys { uint32_t a[NEDGE]; uint32_t b[NEDGE]; };

// Single-instruction rotate (v_alignbit_b32 via fshl).
#if __has_builtin(__builtin_rotateleft32)
#define ROTL32(x, r) __builtin_rotateleft32((x), (r))
#else
#define ROTL32(x, r) (((x) << (r)) | ((x) >> (32 - (r))))
#endif

// JAX Threefry-2x32, 20 rounds. Matches jax/_src/prng.py exactly.
#define TF_R(r) do { x0 += x1; x1 = ROTL32(x1, r); x1 ^= x0; } while (0)
__host__ __device__ inline void tf2x32(uint32_t k0, uint32_t k1,
                                       uint32_t x0, uint32_t x1,
                                       uint32_t& o0, uint32_t& o1) {
  const uint32_t ks2 = k0 ^ k1 ^ 0x1BD11BDAu;
  x0 += k0; x1 += k1;
  TF_R(13); TF_R(15); TF_R(26); TF_R(6);
  x0 += k1; x1 += ks2 + 1u;
  TF_R(17); TF_R(29); TF_R(16); TF_R(24);
  x0 += ks2; x1 += k0 + 2u;
  TF_R(13); TF_R(15); TF_R(26); TF_R(6);
  x0 += k0; x1 += k1 + 3u;
  TF_R(17); TF_R(29); TF_R(16); TF_R(24);
  x0 += k1; x1 += ks2 + 4u;
  TF_R(13); TF_R(15); TF_R(26); TF_R(6);
  x0 += ks2; x1 += k0 + 5u;
  o0 = x0; o1 = x1;
}

// Partitionable threefry bits for linear position p: o0^o1 of tf(key; 0, p).
__device__ __forceinline__ uint32_t tf_bits(uint32_t k0, uint32_t k1, uint32_t p) {
  uint32_t o0, o1;
  tf2x32(k0, k1, 0u, p, o0, o1);
  return o0 ^ o1;
}

// bits -> uniform(1e-10,1) -> gumbel, replicating JAX's exact f32 op sequence
// (separate mul/add rounding — no FMA contraction), double-precision logs.
__device__ __forceinline__ float gumbel_bits(uint32_t bits) {
  float f = __uint_as_float((bits >> 9) | 0x3F800000u) - 1.0f;
  float u = fmaxf(1e-10f, __fadd_rn(__fmul_rn(f, 1.0f - 1e-10f), 1e-10f));
  float t = -(float)log((double)u);
  return -(float)log((double)t);
}

// Phase A: logits[b][n] = W2 . tanh(W1^T [curr_b; nodes_bn] + b1) + b2
__global__ __launch_bounds__(256) void k_logits(
    const float* __restrict__ nodes, const int* __restrict__ nn,
    const float* __restrict__ W1, const float* __restrict__ b1,
    const float* __restrict__ W2, const float* __restrict__ b2,
    float* __restrict__ logits) {
  const int lane = threadIdx.x & 63;
  const int gw = (blockIdx.x * 256 + threadIdx.x) >> 6;   // wave id = (b,n)
  const int b = gw >> 10, n = gw & (NDIM - 1);
  const int cn = nn[b];
  const float a = nodes[((size_t)b * NDIM + cn) * DDIM + lane];  // curr
  const float x = nodes[((size_t)b * NDIM + n) * DDIM + lane];
  float acc = b1[lane];
#pragma unroll 8
  for (int k = 0; k < 64; ++k)
    acc = fmaf(__shfl(a, k), W1[k * DDIM + lane], acc);
#pragma unroll 8
  for (int k = 0; k < 64; ++k)
    acc = fmaf(__shfl(x, k), W1[(64 + k) * DDIM + lane], acc);
  float p = tanhf(acc) * W2[lane];
  for (int off = 32; off; off >>= 1) p += __shfl_down(p, off);
  if (lane == 0) logits[b * NDIM + n] = p + b2[0];
}

// Fused phase: 128-thread blocks = 2 waves on 2 ADJACENT rows (cost-matched,
// so the block's residency slot frees as a unit — fixes the r4/r6 33%-Occ
// leak where fast inactive-row waves idled inside 4-wave blocks).
// Diagonal batch swizzle keeps XCD work balanced (r6).
__global__ __launch_bounds__(128) void k_main(
    const float* __restrict__ adj_in, const float* __restrict__ w_in,
    const float* __restrict__ logits, const int* __restrict__ nn_arr,
    float* __restrict__ adj_out, float* __restrict__ w_out, Keys keys) {
  const int tid = threadIdx.x;
  const int lane = tid & 63;
  const int i = blockIdx.x;                 // 0..16383
  const int g = i >> 5;                     // row-pair index 0..511
  const int b = (i + g) & 31;               // diagonal swizzle
  const int r = (g << 1) | (tid >> 6);      // two adjacent rows per block
  const int gw = (b << 10) | r;
  const int nn = nn_arr[b];
  const size_t row = (size_t)gw << 10;

  int bc[NEDGE];
#pragma unroll
  for (int e = 0; e < NEDGE; ++e) bc[e] = NDIM;   // sentinel: no hit

  if (r <= nn) {   // wave-uniform branch
    int bv[NEDGE], bcl[NEDGE];
#pragma unroll
    for (int e = 0; e < NEDGE; ++e) { bv[e] = -1; bcl[e] = NDIM; }
    bool wnz = false;
    for (int c = lane; c <= nn; c += 64) {
      float w = w_in[row + c];
      if (r == nn && c < nn) w = logits[(b << 10) + c];
      wnz |= (w != 0.f);
      const uint32_t p = (uint32_t)row + (uint32_t)c;
#pragma unroll
      for (int e = 0; e < NEDGE; ++e) {
        // gumbel monotone in bits>>9; per-lane c ascending -> strict '>'
        // keeps smallest c per lane automatically.
        const int v = (int)(tf_bits(keys.a[e], keys.b[e], p) >> 9);
        if (v > bv[e]) { bv[e] = v; bcl[e] = c; }
      }
    }
    if (__ballot(wnz)) {
      // float fallback: only rows with nonzero weights (patched logit row)
      uint32_t fk[NEDGE]; int fc[NEDGE];
#pragma unroll
      for (int e = 0; e < NEDGE; ++e) { fk[e] = 0u; fc[e] = NDIM; }
      for (int c = lane; c <= nn; c += 64) {
        float w = w_in[row + c];
        if (r == nn && c < nn) w = logits[(b << 10) + c];
        const uint32_t p = (uint32_t)row + (uint32_t)c;
#pragma unroll
        for (int e = 0; e < NEDGE; ++e) {
          const float pert = w + gumbel_bits(tf_bits(keys.a[e], keys.b[e], p));
          const uint32_t fu = __float_as_uint(pert);
          const uint32_t key = (fu & 0x80000000u) ? ~fu : (fu | 0x80000000u);
          if (key > fk[e]) { fk[e] = key; fc[e] = c; }
        }
      }
#pragma unroll
      for (int e = 0; e < NEDGE; ++e) {
        uint32_t k = fk[e]; int c = fc[e];
        for (int off = 32; off; off >>= 1) {
          const uint32_t ko = __shfl_xor(k, off);
          const int co = __shfl_xor(c, off);
          if (ko > k || (ko == k && co < c)) { k = ko; c = co; }
        }
        bc[e] = c;   // butterfly: all lanes hold the result
      }
    } else {
#pragma unroll
      for (int e = 0; e < NEDGE; ++e) {
        int v = bv[e]; int c = bcl[e];
        for (int off = 32; off; off >>= 1) {
          const int vo = __shfl_xor(v, off);
          const int co = __shfl_xor(c, off);
          if (vo > v || (vo == v && co < c)) { v = vo; c = co; }
        }
        bc[e] = c;
      }
    }
  }

  // Streaming epilogue: 4 float4 per lane per row, lane-coalesced.
  const float4* a4 = (const float4*)(adj_in + row);
  const float4* w4 = (const float4*)(w_in + row);
  float4* ao4 = (float4*)(adj_out + row);
  float4* wo4 = (float4*)(w_out + row);
  const bool patch = (r == nn);
#pragma unroll
  for (int k = 0; k < 4; ++k) {
    const int idx = (k << 6) | lane;
    float4 v = a4[idx];
    float4 wv = w4[idx];
    float* vf = (float*)&v;
    float* wf = (float*)&wv;
    const int c0 = idx << 2;
#pragma unroll
    for (int jx = 0; jx < 4; ++jx) {
      const int c = c0 + jx;
      float f = vf[jx];
      if (c == bc[0] || c == bc[1] || c == bc[2] || c == bc[3] || c == bc[4])
        f = 1.0f;
      if (c == r) f = 0.0f;
      vf[jx] = f;
      if (patch && c < nn) wf[jx] = logits[(b << 10) + c];
    }
    ao4[idx] = v;
    wo4[idx] = wv;
  }
}

extern "C" void kernel_launch(void* const* d_in, const int* in_sizes, int n_in,
                              void* d_out, int out_size, void* d_ws, size_t ws_size,
                              hipStream_t stream) {
  (void)in_sizes; (void)n_in; (void)out_size; (void)ws_size;
  const float* nodes = (const float*)d_in[0];
  const float* adj   = (const float*)d_in[1];
  const float* wts   = (const float*)d_in[2];
  const int*   nn    = (const int*)d_in[3];
  const float* W1    = (const float*)d_in[5];
  const float* b1    = (const float*)d_in[6];
  const float* W2    = (const float*)d_in[7];
  const float* b2    = (const float*)d_in[8];

  float* adj_out = (float*)d_out;
  float* w_out   = adj_out + (size_t)BDIM * NDIM * NDIM;
  float* logits  = (float*)d_ws;  // 32*1024 floats = 128 KB

  // folded keys: k_i = threefry2x32(key=(0,42), data=(0,i))  [jax.random.fold_in]
  Keys keys;
  for (int i = 0; i < NEDGE; ++i) {
    uint32_t o0, o1;
    tf2x32(0u, 42u, 0u, (uint32_t)i, o0, o1);
    keys.a[i] = o0; keys.b[i] = o1;
  }

  k_logits<<<dim3(BDIM * NDIM / 4), 256, 0, stream>>>(nodes, nn, W1, b1, W2, b2, logits);
  k_main  <<<dim3(BDIM * NDIM / 2), 128, 0, stream>>>(adj, wts, logits, nn, adj_out, w_out, keys);
}

// Round 9
// 283.664 us; speedup vs baseline: 1.9181x; 1.0306x over previous
//
#include <hip/hip_runtime.h>
#include <hip/hip_bf16.h>
#include <cstdint>
#include <math.h>

#define NDIM 1024
#define BDIM 32
#define DDIM 64
#define NEDGE 5

struct Keys { uint32_t a[NEDGE]; uint32_t b[NEDGE]; };

// Single-instruction rotate (v_alignbit_b32 via fshl).
#if __has_builtin(__builtin_rotateleft32)
#define ROTL32(x, r) __builtin_rotateleft32((x), (r))
#else
#define ROTL32(x, r) (((x) << (r)) | ((x) >> (32 - (r))))
#endif

// JAX Threefry-2x32, 20 rounds. Matches jax/_src/prng.py exactly.
#define TF_R(r) do { x0 += x1; x1 = ROTL32(x1, r); x1 ^= x0; } while (0)
__host__ __device__ inline void tf2x32(uint32_t k0, uint32_t k1,
                                       uint32_t x0, uint32_t x1,
                                       uint32_t& o0, uint32_t& o1) {
  const uint32_t ks2 = k0 ^ k1 ^ 0x1BD11BDAu;
  x0 += k0; x1 += k1;
  TF_R(13); TF_R(15); TF_R(26); TF_R(6);
  x0 += k1; x1 += ks2 + 1u;
  TF_R(17); TF_R(29); TF_R(16); TF_R(24);
  x0 += ks2; x1 += k0 + 2u;
  TF_R(13); TF_R(15); TF_R(26); TF_R(6);
  x0 += k0; x1 += k1 + 3u;
  TF_R(17); TF_R(29); TF_R(16); TF_R(24);
  x0 += k1; x1 += ks2 + 4u;
  TF_R(13); TF_R(15); TF_R(26); TF_R(6);
  x0 += ks2; x1 += k0 + 5u;
  o0 = x0; o1 = x1;
}

// Partitionable threefry bits for linear position p: o0^o1 of tf(key; 0, p).
__device__ __forceinline__ uint32_t tf_bits(uint32_t k0, uint32_t k1, uint32_t p) {
  uint32_t o0, o1;
  tf2x32(k0, k1, 0u, p, o0, o1);
  return o0 ^ o1;
}

// bits -> uniform(1e-10,1) -> gumbel, replicating JAX's exact f32 op sequence
// (separate mul/add rounding — no FMA contraction), double-precision logs.
__device__ __forceinline__ float gumbel_bits(uint32_t bits) {
  float f = __uint_as_float((bits >> 9) | 0x3F800000u) - 1.0f;
  float u = fmaxf(1e-10f, __fadd_rn(__fmul_rn(f, 1.0f - 1e-10f), 1e-10f));
  float t = -(float)log((double)u);
  return -(float)log((double)t);
}

// Phase A: logits[b][n] = W2 . tanh(W1^T [curr_b; nodes_bn] + b1) + b2
__global__ __launch_bounds__(256) void k_logits(
    const float* __restrict__ nodes, const int* __restrict__ nn,
    const float* __restrict__ W1, const float* __restrict__ b1,
    const float* __restrict__ W2, const float* __restrict__ b2,
    float* __restrict__ logits) {
  const int lane = threadIdx.x & 63;
  const int gw = (blockIdx.x * 256 + threadIdx.x) >> 6;   // wave id = (b,n)
  const int b = gw >> 10, n = gw & (NDIM - 1);
  const int cn = nn[b];
  const float a = nodes[((size_t)b * NDIM + cn) * DDIM + lane];  // curr
  const float x = nodes[((size_t)b * NDIM + n) * DDIM + lane];
  float acc = b1[lane];
#pragma unroll 8
  for (int k = 0; k < 64; ++k)
    acc = fmaf(__shfl(a, k), W1[k * DDIM + lane], acc);
#pragma unroll 8
  for (int k = 0; k < 64; ++k)
    acc = fmaf(__shfl(x, k), W1[(64 + k) * DDIM + lane], acc);
  float p = tanhf(acc) * W2[lane];
  for (int off = 32; off; off >>= 1) p += __shfl_down(p, off);
  if (lane == 0) logits[b * NDIM + n] = p + b2[0];
}

// Fused phase: one wave per row; 2 adjacent rows per 128-thread block;
// diagonal batch swizzle (r6). NEW in r9: preload adj+weights rows into
// registers FIRST, then run a PURE-VALU hash loop (no VMEM -> no per-iter
// waitcnt stalls -> load latency hides under ~6000cy of hashing), epilogue
// writes from registers.
__global__ __launch_bounds__(128) void k_main(
    const float* __restrict__ adj_in, const float* __restrict__ w_in,
    const float* __restrict__ logits, const int* __restrict__ nn_arr,
    float* __restrict__ adj_out, float* __restrict__ w_out, Keys keys) {
  const int tid = threadIdx.x;
  const int lane = tid & 63;
  const int i = blockIdx.x;                 // 0..16383
  const int g = i >> 5;                     // row-pair index 0..511
  const int b = (i + g) & 31;               // diagonal swizzle
  const int r = (g << 1) | (tid >> 6);      // two adjacent rows per block
  const int gw = (b << 10) | r;
  const int nn = nn_arr[b];
  const size_t row = (size_t)gw << 10;

  // ---- preload both rows into registers (latency hidden under hash) ----
  const float4* a4 = (const float4*)(adj_in + row);
  const float4* w4 = (const float4*)(w_in + row);
  float4 av[4], wv[4];
#pragma unroll
  for (int k = 0; k < 4; ++k) {
    av[k] = a4[(k << 6) | lane];
    wv[k] = w4[(k << 6) | lane];
  }
  const bool patch = (r == nn);             // wave-uniform
  if (patch) {
    const float4* l4 = (const float4*)(logits + (b << 10));
#pragma unroll
    for (int k = 0; k < 4; ++k) {
      const float4 lv = l4[(k << 6) | lane];
      float* wf = (float*)&wv[k];
      const float* lf = (const float*)&lv;
      const int c0 = ((k << 6) | lane) << 2;
#pragma unroll
      for (int jx = 0; jx < 4; ++jx)
        if (c0 + jx < nn) wf[jx] = lf[jx];
    }
  }

  int bc[NEDGE];
#pragma unroll
  for (int e = 0; e < NEDGE; ++e) bc[e] = NDIM;   // sentinel: no hit

  if (r <= nn) {   // wave-uniform branch
    // wnz from the register-held (already patched) weights row
    bool wnz = false;
#pragma unroll
    for (int k = 0; k < 4; ++k) {
      const float* wf = (const float*)&wv[k];
      const int c0 = ((k << 6) | lane) << 2;
#pragma unroll
      for (int jx = 0; jx < 4; ++jx)
        wnz |= ((c0 + jx <= nn) && (wf[jx] != 0.f));
    }

    if (__ballot(wnz)) {
      // float fallback (rare: the patched logit row) — global re-read is fine
      uint32_t fk[NEDGE]; int fc[NEDGE];
#pragma unroll
      for (int e = 0; e < NEDGE; ++e) { fk[e] = 0u; fc[e] = NDIM; }
      for (int c = lane; c <= nn; c += 64) {
        float w = w_in[row + c];
        if (r == nn && c < nn) w = logits[(b << 10) + c];
        const uint32_t p = (uint32_t)row + (uint32_t)c;
#pragma unroll
        for (int e = 0; e < NEDGE; ++e) {
          const float pert = w + gumbel_bits(tf_bits(keys.a[e], keys.b[e], p));
          const uint32_t fu = __float_as_uint(pert);
          const uint32_t key = (fu & 0x80000000u) ? ~fu : (fu | 0x80000000u);
          if (key > fk[e]) { fk[e] = key; fc[e] = c; }
        }
      }
#pragma unroll
      for (int e = 0; e < NEDGE; ++e) {
        uint32_t k = fk[e]; int c = fc[e];
        for (int off = 32; off; off >>= 1) {
          const uint32_t ko = __shfl_xor(k, off);
          const int co = __shfl_xor(c, off);
          if (ko > k || (ko == k && co < c)) { k = ko; c = co; }
        }
        bc[e] = c;   // butterfly: all lanes hold the result
      }
    } else {
      // pure-VALU int path: no memory ops anywhere in this loop
      int bv[NEDGE], bcl[NEDGE];
#pragma unroll
      for (int e = 0; e < NEDGE; ++e) { bv[e] = -1; bcl[e] = NDIM; }
      for (int c = lane; c <= nn; c += 64) {
        const uint32_t p = (uint32_t)row + (uint32_t)c;
#pragma unroll
        for (int e = 0; e < NEDGE; ++e) {
          // gumbel monotone in bits>>9; per-lane c ascending -> strict '>'
          // keeps smallest c per lane automatically.
          const int v = (int)(tf_bits(keys.a[e], keys.b[e], p) >> 9);
          if (v > bv[e]) { bv[e] = v; bcl[e] = c; }
        }
      }
#pragma unroll
      for (int e = 0; e < NEDGE; ++e) {
        int v = bv[e]; int c = bcl[e];
        for (int off = 32; off; off >>= 1) {
          const int vo = __shfl_xor(v, off);
          const int co = __shfl_xor(c, off);
          if (vo > v || (vo == v && co < c)) { v = vo; c = co; }
        }
        bc[e] = c;
      }
    }
  }

  // Epilogue from registers: OR-in hits, zero diag, store both rows.
  float4* ao4 = (float4*)(adj_out + row);
  float4* wo4 = (float4*)(w_out + row);
#pragma unroll
  for (int k = 0; k < 4; ++k) {
    const int idx = (k << 6) | lane;
    float* vf = (float*)&av[k];
    const int c0 = idx << 2;
#pragma unroll
    for (int jx = 0; jx < 4; ++jx) {
      const int c = c0 + jx;
      float f = vf[jx];
      if (c == bc[0] || c == bc[1] || c == bc[2] || c == bc[3] || c == bc[4])
        f = 1.0f;
      if (c == r) f = 0.0f;
      vf[jx] = f;
    }
    ao4[idx] = av[k];
    wo4[idx] = wv[k];
  }
}

extern "C" void kernel_launch(void* const* d_in, const int* in_sizes, int n_in,
                              void* d_out, int out_size, void* d_ws, size_t ws_size,
                              hipStream_t stream) {
  (void)in_sizes; (void)n_in; (void)out_size; (void)ws_size;
  const float* nodes = (const float*)d_in[0];
  const float* adj   = (const float*)d_in[1];
  const float* wts   = (const float*)d_in[2];
  const int*   nn    = (const int*)d_in[3];
  const float* W1    = (const float*)d_in[5];
  const float* b1    = (const float*)d_in[6];
  const float* W2    = (const float*)d_in[7];
  const float* b2    = (const float*)d_in[8];

  float* adj_out = (float*)d_out;
  float* w_out   = adj_out + (size_t)BDIM * NDIM * NDIM;
  float* logits  = (float*)d_ws;  // 32*1024 floats = 128 KB

  // folded keys: k_i = threefry2x32(key=(0,42), data=(0,i))  [jax.random.fold_in]
  Keys keys;
  for (int i = 0; i < NEDGE; ++i) {
    uint32_t o0, o1;
    tf2x32(0u, 42u, 0u, (uint32_t)i, o0, o1);
    keys.a[i] = o0; keys.b[i] = o1;
  }

  k_logits<<<dim3(BDIM * NDIM / 4), 256, 0, stream>>>(nodes, nn, W1, b1, W2, b2, logits);
  k_main  <<<dim3(BDIM * NDIM / 2), 128, 0, stream>>>(adj, wts, logits, nn, adj_out, w_out, keys);
}

// Round 10
// 248.242 us; speedup vs baseline: 2.1918x; 1.1427x over previous
//
#include <hip/hip_runtime.h>
#include <hip/hip_bf16.h>
#include <cstdint>
#include <math.h>

#define NDIM 1024
#define BDIM 32
#define DDIM 64
#define NEDGE 5

struct Keys { uint32_t a[NEDGE]; uint32_t b[NEDGE]; };

// Single-instruction rotate (v_alignbit_b32 via fshl).
#if __has_builtin(__builtin_rotateleft32)
#define ROTL32(x, r) __builtin_rotateleft32((x), (r))
#else
#define ROTL32(x, r) (((x) << (r)) | ((x) >> (32 - (r))))
#endif

// JAX Threefry-2x32, 20 rounds. Matches jax/_src/prng.py exactly.
#define TF_R(r) do { x0 += x1; x1 = ROTL32(x1, r); x1 ^= x0; } while (0)
__host__ __device__ inline void tf2x32(uint32_t k0, uint32_t k1,
                                       uint32_t x0, uint32_t x1,
                                       uint32_t& o0, uint32_t& o1) {
  const uint32_t ks2 = k0 ^ k1 ^ 0x1BD11BDAu;
  x0 += k0; x1 += k1;
  TF_R(13); TF_R(15); TF_R(26); TF_R(6);
  x0 += k1; x1 += ks2 + 1u;
  TF_R(17); TF_R(29); TF_R(16); TF_R(24);
  x0 += ks2; x1 += k0 + 2u;
  TF_R(13); TF_R(15); TF_R(26); TF_R(6);
  x0 += k0; x1 += k1 + 3u;
  TF_R(17); TF_R(29); TF_R(16); TF_R(24);
  x0 += k1; x1 += ks2 + 4u;
  TF_R(13); TF_R(15); TF_R(26); TF_R(6);
  x0 += ks2; x1 += k0 + 5u;
  o0 = x0; o1 = x1;
}

// Partitionable threefry bits for linear position p: o0^o1 of tf(key; 0, p).
__device__ __forceinline__ uint32_t tf_bits(uint32_t k0, uint32_t k1, uint32_t p) {
  uint32_t o0, o1;
  tf2x32(k0, k1, 0u, p, o0, o1);
  return o0 ^ o1;
}

// DUAL-counter variant: two independent hash chains with statement-level
// interleaving, so the scheduler always has a ready instruction while the
// other chain's dep completes (threefry is serial within one chain).
#define TFD(r) do { a0 += a1; b0 += b1; \
                    a1 = ROTL32(a1, r); b1 = ROTL32(b1, r); \
                    a1 ^= a0; b1 ^= b0; } while (0)
__device__ __forceinline__ void tf_bits_x2(uint32_t k0, uint32_t k1,
                                           uint32_t pA, uint32_t pB,
                                           uint32_t& oA, uint32_t& oB) {
  const uint32_t ks2 = k0 ^ k1 ^ 0x1BD11BDAu;
  uint32_t a0 = k0, a1 = pA + k1;
  uint32_t b0 = k0, b1 = pB + k1;
  TFD(13); TFD(15); TFD(26); TFD(6);
  a0 += k1; a1 += ks2 + 1u;  b0 += k1; b1 += ks2 + 1u;
  TFD(17); TFD(29); TFD(16); TFD(24);
  a0 += ks2; a1 += k0 + 2u;  b0 += ks2; b1 += k0 + 2u;
  TFD(13); TFD(15); TFD(26); TFD(6);
  a0 += k0; a1 += k1 + 3u;   b0 += k0; b1 += k1 + 3u;
  TFD(17); TFD(29); TFD(16); TFD(24);
  a0 += k1; a1 += ks2 + 4u;  b0 += k1; b1 += ks2 + 4u;
  TFD(13); TFD(15); TFD(26); TFD(6);
  a0 += ks2; a1 += k0 + 5u;  b0 += ks2; b1 += k0 + 5u;
  oA = a0 ^ a1; oB = b0 ^ b1;
}

// bits -> uniform(1e-10,1) -> gumbel, replicating JAX's exact f32 op sequence
// (separate mul/add rounding — no FMA contraction), double-precision logs.
__device__ __forceinline__ float gumbel_bits(uint32_t bits) {
  float f = __uint_as_float((bits >> 9) | 0x3F800000u) - 1.0f;
  float u = fmaxf(1e-10f, __fadd_rn(__fmul_rn(f, 1.0f - 1e-10f), 1e-10f));
  float t = -(float)log((double)u);
  return -(float)log((double)t);
}

// Phase A: logits[b][n] = W2 . tanh(W1^T [curr_b; nodes_bn] + b1) + b2
__global__ __launch_bounds__(256) void k_logits(
    const float* __restrict__ nodes, const int* __restrict__ nn,
    const float* __restrict__ W1, const float* __restrict__ b1,
    const float* __restrict__ W2, const float* __restrict__ b2,
    float* __restrict__ logits) {
  const int lane = threadIdx.x & 63;
  const int gw = (blockIdx.x * 256 + threadIdx.x) >> 6;   // wave id = (b,n)
  const int b = gw >> 10, n = gw & (NDIM - 1);
  const int cn = nn[b];
  const float a = nodes[((size_t)b * NDIM + cn) * DDIM + lane];  // curr
  const float x = nodes[((size_t)b * NDIM + n) * DDIM + lane];
  float acc = b1[lane];
#pragma unroll 8
  for (int k = 0; k < 64; ++k)
    acc = fmaf(__shfl(a, k), W1[k * DDIM + lane], acc);
#pragma unroll 8
  for (int k = 0; k < 64; ++k)
    acc = fmaf(__shfl(x, k), W1[(64 + k) * DDIM + lane], acc);
  float p = tanhf(acc) * W2[lane];
  for (int off = 32; off; off >>= 1) p += __shfl_down(p, off);
  if (lane == 0) logits[b * NDIM + n] = p + b2[0];
}

// Fused phase: one wave per row; 2 adjacent rows per 128-thread block;
// diagonal batch swizzle (r6); register preload + register epilogue (r9).
// NEW in r10: 2 positions per lane per iteration (c and c+64, stride 128)
// via the interleaved dual-hash — 10 independent chains fill dep bubbles.
__global__ __launch_bounds__(128) void k_main(
    const float* __restrict__ adj_in, const float* __restrict__ w_in,
    const float* __restrict__ logits, const int* __restrict__ nn_arr,
    float* __restrict__ adj_out, float* __restrict__ w_out, Keys keys) {
  const int tid = threadIdx.x;
  const int lane = tid & 63;
  const int i = blockIdx.x;                 // 0..16383
  const int g = i >> 5;                     // row-pair index 0..511
  const int b = (i + g) & 31;               // diagonal swizzle
  const int r = (g << 1) | (tid >> 6);      // two adjacent rows per block
  const int gw = (b << 10) | r;
  const int nn = nn_arr[b];
  const size_t row = (size_t)gw << 10;

  // ---- preload both rows into registers (latency hidden under hash) ----
  const float4* a4 = (const float4*)(adj_in + row);
  const float4* w4 = (const float4*)(w_in + row);
  float4 av[4], wv[4];
#pragma unroll
  for (int k = 0; k < 4; ++k) {
    av[k] = a4[(k << 6) | lane];
    wv[k] = w4[(k << 6) | lane];
  }
  const bool patch = (r == nn);             // wave-uniform
  if (patch) {
    const float4* l4 = (const float4*)(logits + (b << 10));
#pragma unroll
    for (int k = 0; k < 4; ++k) {
      const float4 lv = l4[(k << 6) | lane];
      float* wf = (float*)&wv[k];
      const float* lf = (const float*)&lv;
      const int c0 = ((k << 6) | lane) << 2;
#pragma unroll
      for (int jx = 0; jx < 4; ++jx)
        if (c0 + jx < nn) wf[jx] = lf[jx];
    }
  }

  int bc[NEDGE];
#pragma unroll
  for (int e = 0; e < NEDGE; ++e) bc[e] = NDIM;   // sentinel: no hit

  if (r <= nn) {   // wave-uniform branch
    // wnz from the register-held (already patched) weights row
    bool wnz = false;
#pragma unroll
    for (int k = 0; k < 4; ++k) {
      const float* wf = (const float*)&wv[k];
      const int c0 = ((k << 6) | lane) << 2;
#pragma unroll
      for (int jx = 0; jx < 4; ++jx)
        wnz |= ((c0 + jx <= nn) && (wf[jx] != 0.f));
    }

    if (__ballot(wnz)) {
      // float fallback (rare: the patched logit row) — global re-read is fine
      uint32_t fk[NEDGE]; int fc[NEDGE];
#pragma unroll
      for (int e = 0; e < NEDGE; ++e) { fk[e] = 0u; fc[e] = NDIM; }
      for (int c = lane; c <= nn; c += 64) {
        float w = w_in[row + c];
        if (r == nn && c < nn) w = logits[(b << 10) + c];
        const uint32_t p = (uint32_t)row + (uint32_t)c;
#pragma unroll
        for (int e = 0; e < NEDGE; ++e) {
          const float pert = w + gumbel_bits(tf_bits(keys.a[e], keys.b[e], p));
          const uint32_t fu = __float_as_uint(pert);
          const uint32_t key = (fu & 0x80000000u) ? ~fu : (fu | 0x80000000u);
          if (key > fk[e]) { fk[e] = key; fc[e] = c; }
        }
      }
#pragma unroll
      for (int e = 0; e < NEDGE; ++e) {
        uint32_t k = fk[e]; int c = fc[e];
        for (int off = 32; off; off >>= 1) {
          const uint32_t ko = __shfl_xor(k, off);
          const int co = __shfl_xor(c, off);
          if (ko > k || (ko == k && co < c)) { k = ko; c = co; }
        }
        bc[e] = c;   // butterfly: all lanes hold the result
      }
    } else {
      // pure-VALU int path, 2 positions/lane/iter (10 interleaved chains)
      int bvA[NEDGE], bcA[NEDGE], bvB[NEDGE], bcB[NEDGE];
#pragma unroll
      for (int e = 0; e < NEDGE; ++e) {
        bvA[e] = -1; bcA[e] = NDIM; bvB[e] = -1; bcB[e] = NDIM;
      }
      const uint32_t pbase = (uint32_t)row;
      for (int c = lane; c <= nn; c += 128) {
        const uint32_t pA = pbase + (uint32_t)c;
        const int cB = c + 64;
        const bool okB = (cB <= nn);          // per-lane predicate
#pragma unroll
        for (int e = 0; e < NEDGE; ++e) {
          uint32_t oA, oB;
          tf_bits_x2(keys.a[e], keys.b[e], pA, pA + 64u, oA, oB);
          const int vA = (int)(oA >> 9);
          const int vB = okB ? (int)(oB >> 9) : -1;
          // strict '>' + ascending c keeps smallest c per stream
          if (vA > bvA[e]) { bvA[e] = vA; bcA[e] = c; }
          if (vB > bvB[e]) { bvB[e] = vB; bcB[e] = cB; }
        }
      }
      // merge streams (tie -> smaller c), then butterfly across lanes
#pragma unroll
      for (int e = 0; e < NEDGE; ++e) {
        int v = bvA[e], c = bcA[e];
        if (bvB[e] > v || (bvB[e] == v && bcB[e] < c)) { v = bvB[e]; c = bcB[e]; }
        for (int off = 32; off; off >>= 1) {
          const int vo = __shfl_xor(v, off);
          const int co = __shfl_xor(c, off);
          if (vo > v || (vo == v && co < c)) { v = vo; c = co; }
        }
        bc[e] = c;
      }
    }
  }

  // Epilogue from registers: OR-in hits, zero diag, store both rows.
  float4* ao4 = (float4*)(adj_out + row);
  float4* wo4 = (float4*)(w_out + row);
#pragma unroll
  for (int k = 0; k < 4; ++k) {
    const int idx = (k << 6) | lane;
    float* vf = (float*)&av[k];
    const int c0 = idx << 2;
#pragma unroll
    for (int jx = 0; jx < 4; ++jx) {
      const int c = c0 + jx;
      float f = vf[jx];
      if (c == bc[0] || c == bc[1] || c == bc[2] || c == bc[3] || c == bc[4])
        f = 1.0f;
      if (c == r) f = 0.0f;
      vf[jx] = f;
    }
    ao4[idx] = av[k];
    wo4[idx] = wv[k];
  }
}

extern "C" void kernel_launch(void* const* d_in, const int* in_sizes, int n_in,
                              void* d_out, int out_size, void* d_ws, size_t ws_size,
                              hipStream_t stream) {
  (void)in_sizes; (void)n_in; (void)out_size; (void)ws_size;
  const float* nodes = (const float*)d_in[0];
  const float* adj   = (const float*)d_in[1];
  const float* wts   = (const float*)d_in[2];
  const int*   nn    = (const int*)d_in[3];
  const float* W1    = (const float*)d_in[5];
  const float* b1    = (const float*)d_in[6];
  const float* W2    = (const float*)d_in[7];
  const float* b2    = (const float*)d_in[8];

  float* adj_out = (float*)d_out;
  float* w_out   = adj_out + (size_t)BDIM * NDIM * NDIM;
  float* logits  = (float*)d_ws;  // 32*1024 floats = 128 KB

  // folded keys: k_i = threefry2x32(key=(0,42), data=(0,i))  [jax.random.fold_in]
  Keys keys;
  for (int i = 0; i < NEDGE; ++i) {
    uint32_t o0, o1;
    tf2x32(0u, 42u, 0u, (uint32_t)i, o0, o1);
    keys.a[i] = o0; keys.b[i] = o1;
  }

  k_logits<<<dim3(BDIM * NDIM / 4), 256, 0, stream>>>(nodes, nn, W1, b1, W2, b2, logits);
  k_main  <<<dim3(BDIM * NDIM / 2), 128, 0, stream>>>(adj, wts, logits, nn, adj_out, w_out, keys);
}